// Round 12
// baseline (95.759 us; speedup 1.0000x reference)
//
#include <hip/hip_runtime.h>

#define DD 64

typedef float f4v __attribute__((ext_vector_type(4)));

// record: node (17b) | etype (9b) | w (1b)
#define PACK(n, t, w) ((((unsigned)(n)) << 10) | (((unsigned)(t)) << 1) | (unsigned)(w))

// Zero-fill [lo4, hi4) float4 slots with PLAIN stores (R11 A/B winner),
// 4 independent stores per iteration.
__device__ __forceinline__ void fill_zero(float* __restrict__ out, size_t lo4,
                                          size_t hi4, int tid, int nth) {
    f4v z = (f4v)(0.f);
    f4v* p = (f4v*)out;
    size_t stride = (size_t)nth;
    size_t i = lo4 + (size_t)tid;
    for (; i + 3 * stride < hi4; i += 4 * stride) {
        p[i] = z;
        p[i + stride] = z;
        p[i + 2 * stride] = z;
        p[i + 3 * stride] = z;
    }
    for (; i < hi4; i += stride) p[i] = z;
}

// ---------------------------------------------------------------------------
// Node 1: zero bitmap+counters, rel_ctx mean, query-bit marking (one block).
__global__ __launch_bounds__(512) void k_ctx(const float* __restrict__ rel, int R,
                                             const int* __restrict__ h_index, int B,
                                             float* __restrict__ ctx,
                                             unsigned* __restrict__ bitmap, int NB,
                                             int* __restrict__ counters) {
    __shared__ float part[8][DD];
    int t = threadIdx.x;
    for (int i = t; i < NB; i += 512) bitmap[i] = 0u;
    if (t < 2) counters[t] = 0;
    int lane = t & 63;
    int w = t >> 6;
    float s0 = 0.f, s1 = 0.f;
    int r = w;
    for (; r + 16 <= R; r += 16) {
        s0 += rel[(size_t)r * DD + lane];
        s1 += rel[(size_t)(r + 8) * DD + lane];
    }
    for (; r < R; r += 8) s0 += rel[(size_t)r * DD + lane];
    part[w][lane] = s0 + s1;
    __syncthreads();
    if (t < DD) {
        float tot = 0.f;
#pragma unroll
        for (int i = 0; i < 8; ++i) tot += part[i][t];
        ctx[t] = tot / (float)R;
    }
    if (t < B) {
        int n = h_index[t];
        atomicOr(bitmap + ((unsigned)n >> 5), 1u << (n & 31));
    }
}

// ---------------------------------------------------------------------------
// Node 2: mark 1-hop neighbors + ENTIRE 205 MB zero-fill (4096 blocks).
__device__ __forceinline__ bool is_q(int v, const int* hq) {
    bool m = false;
#pragma unroll
    for (int b = 0; b < 8; ++b) m |= (v == hq[b]);
    return m;
}

__global__ __launch_bounds__(256) void k_markfill(const int* __restrict__ src,
                                                  const int* __restrict__ dst,
                                                  const int* __restrict__ h_index, int B,
                                                  unsigned* __restrict__ bitmap, int E,
                                                  float* __restrict__ out, size_t total4) {
    int hq[8];
#pragma unroll
    for (int b = 0; b < 8; ++b) hq[b] = (b < B) ? h_index[b] : -1;
    const int nth = gridDim.x * blockDim.x;
    const int tid = blockIdx.x * blockDim.x + threadIdx.x;
    const int E16 = E & ~15;
#define MARK1(sv, dv)                                                        \
    do {                                                                     \
        if (is_q(sv, hq)) atomicOr(bitmap + ((unsigned)(dv) >> 5), 1u << ((dv) & 31)); \
        if (is_q(dv, hq)) atomicOr(bitmap + ((unsigned)(sv) >> 5), 1u << ((sv) & 31)); \
    } while (0)
    for (int base = tid * 16; base < E16; base += nth * 16) {
        int4 s[4], d[4];
#pragma unroll
        for (int u = 0; u < 4; ++u) s[u] = *(const int4*)(src + base + u * 4);
#pragma unroll
        for (int u = 0; u < 4; ++u) d[u] = *(const int4*)(dst + base + u * 4);
#pragma unroll
        for (int u = 0; u < 4; ++u) {
            MARK1(s[u].x, d[u].x); MARK1(s[u].y, d[u].y);
            MARK1(s[u].z, d[u].z); MARK1(s[u].w, d[u].w);
        }
    }
    for (int e = E16 + tid; e < E; e += nth) MARK1(src[e], dst[e]);
#undef MARK1
    fill_zero(out, 0, total4, tid, nth);
}

// ---------------------------------------------------------------------------
// Node 3: slim scan-only kernel: compact + edge scan #2 -> packed records.
__global__ __launch_bounds__(256) void k_scan(const int* __restrict__ src,
                                              const int* __restrict__ dst,
                                              const int* __restrict__ etype,
                                              const unsigned* __restrict__ bitmap, int NB,
                                              int* __restrict__ rel_list,
                                              unsigned* __restrict__ rlist,
                                              int* __restrict__ counters, int E) {
    extern __shared__ unsigned bm[];
    const int lane = threadIdx.x & 63;
    const int tid = blockIdx.x * blockDim.x + threadIdx.x;
    const int nth = gridDim.x * blockDim.x;
    // ---- (a) compact: bitmap word -> rel_list (fully converged) ----
    for (int i = tid; i < ((NB + nth - 1) / nth) * nth; i += nth) {
        unsigned word = (i < NB) ? bitmap[i] : 0u;
        int c = __popc(word);
        int incl = c;
#pragma unroll
        for (int sh = 1; sh < 64; sh <<= 1) {
            int t = __shfl_up(incl, sh);
            if (lane >= sh) incl += t;
        }
        int total = __shfl(incl, 63);
        if (total > 0) {
            int b0 = 0;
            if (lane == 0) b0 = atomicAdd(counters + 0, total);
            b0 = __shfl(b0, 0);
            int off = b0 + incl - c;
            while (word) {
                int bit = __ffs(word) - 1;
                word &= word - 1;
                rel_list[off++] = i * 32 + bit;
            }
        }
    }
    // ---- (b) scan: LDS bitmap, wave-converged chunks ----
    for (int i = threadIdx.x; i < NB; i += blockDim.x) bm[i] = bitmap[i];
    __syncthreads();
#define CHK(id) ((bm[(unsigned)(id) >> 5] >> ((unsigned)(id) & 31)) & 1u)
    const int wid = tid >> 6;
    const int nw = nth >> 6;
    const int E16 = E & ~15;
    const int CH = 64 * 16;
    for (int cb = wid * CH; cb < E16; cb += nw * CH) {
        int base = cb + lane * 16;
        bool act = (base < E16);
        int4 s[4], d[4];
        if (act) {
#pragma unroll
            for (int u = 0; u < 4; ++u) s[u] = *(const int4*)(src + base + u * 4);
#pragma unroll
            for (int u = 0; u < 4; ++u) d[u] = *(const int4*)(dst + base + u * 4);
        }
        unsigned ms = 0u, md = 0u;
        if (act) {
#define TST(sv, dv, idx)                                        \
            do {                                                \
                unsigned bs = CHK(sv), bd = CHK(dv);            \
                unsigned neq = ((sv) != (dv)) ? 1u : 0u;        \
                ms |= bs << (idx);                              \
                md |= (bd & neq) << (idx);                      \
            } while (0)
#pragma unroll
            for (int u = 0; u < 4; ++u) {
                TST(s[u].x, d[u].x, u * 4 + 0);
                TST(s[u].y, d[u].y, u * 4 + 1);
                TST(s[u].z, d[u].z, u * 4 + 2);
                TST(s[u].w, d[u].w, u * 4 + 3);
            }
#undef TST
        }
        int c = __popc(ms) + __popc(md);
        int incl = c;
#pragma unroll
        for (int sh = 1; sh < 64; sh <<= 1) {
            int t = __shfl_up(incl, sh);
            if (lane >= sh) incl += t;
        }
        int total = __shfl(incl, 63);
        if (total == 0) continue;
        int b0 = 0;
        if (lane == 0) b0 = atomicAdd(counters + 1, total);
        b0 = __shfl(b0, 0);
        unsigned off = (unsigned)(b0 + incl - c);
        if (c) {
#define EMIT(sv, dv, idx)                                                     \
            do {                                                              \
                unsigned bit = 1u << (idx);                                   \
                if ((ms | md) & bit) {                                        \
                    int t = etype[base + (idx)];                              \
                    if (ms & bit) rlist[off++] = PACK(sv, t, ((sv) != (dv)) ? 1 : 0); \
                    if (md & bit) rlist[off++] = PACK(dv, t, 1);              \
                }                                                             \
            } while (0)
#pragma unroll
            for (int u = 0; u < 4; ++u) {
                EMIT(s[u].x, d[u].x, u * 4 + 0);
                EMIT(s[u].y, d[u].y, u * 4 + 1);
                EMIT(s[u].z, d[u].z, u * 4 + 2);
                EMIT(s[u].w, d[u].w, u * 4 + 3);
            }
#undef EMIT
        }
    }
    for (int e = E16 + tid; e < E; e += nth) {
        int sv = src[e], dv = dst[e];
        unsigned bs = CHK(sv), bd = CHK(dv);
        unsigned neq = (sv != dv) ? 1u : 0u;
        int k = (int)bs + (int)(bd & neq);
        if (k) {
            int t = etype[e];
            int o = atomicAdd(counters + 1, k);
            if (bs) rlist[o++] = PACK(sv, t, neq);
            if (bd & neq) rlist[o] = PACK(dv, t, 1);
        }
    }
#undef CHK
}

// ---------------------------------------------------------------------------
// Node 4: per relevant node: gather records (4 waves) + MLP + write B planes.
__device__ __forceinline__ void proc_rec(unsigned rv, bool valid, int n,
                                         const float* __restrict__ rel, int lane,
                                         float& fs, int& cnt, int& nb) {
    bool want = valid && ((int)(rv >> 10) == n);
    unsigned long long mk = __ballot(want);
    while (mk) {
        int l = __ffsll(mk) - 1;
        mk &= mk - 1;
        unsigned v = __shfl(rv, l);
        int t = (int)((v >> 1) & 0x1FFu);
        fs += rel[t * DD + lane];
        cnt += 1;
        nb += (int)(v & 1u);
    }
}

__global__ __launch_bounds__(256) void k_gather(
    const int* __restrict__ rel_list, const int* __restrict__ counters,
    const unsigned* __restrict__ rlist,
    const float* __restrict__ rel, const float* __restrict__ ctx,
    const float* __restrict__ Wi1, const float* __restrict__ bi1,
    const float* __restrict__ Wi2, const float* __restrict__ bi2,
    const float* __restrict__ Wc1, const float* __restrict__ bc1,
    const float* __restrict__ Wc2, const float* __restrict__ bc2,
    const float* __restrict__ strength, float* __restrict__ out, int N, int B) {
    __shared__ float part[4][DD];
    __shared__ int pc[4], pn[4];
    int lane = threadIdx.x & 63;
    int wv = threadIdx.x >> 6;
    int C = counters[0];
    int M = counters[1];
    float alpha = fminf(fmaxf(strength[0], 0.f), 0.3f);
    float ctxj = ctx[lane];
    int nchunk = (M + 255) / 256;
    size_t plane = (size_t)N * DD;
    for (int i = blockIdx.x; i < C; i += gridDim.x) {
        int n = rel_list[i];
        float fs = 0.f;
        int cnt = 0, nb = 0;
        for (int ch = wv; ch < nchunk; ch += 4) {
            int bbase = ch * 256 + lane * 4;
            uint4 r = *(const uint4*)(rlist + bbase);   // capacity-padded
            proc_rec(r.x, bbase + 0 < M, n, rel, lane, fs, cnt, nb);
            proc_rec(r.y, bbase + 1 < M, n, rel, lane, fs, cnt, nb);
            proc_rec(r.z, bbase + 2 < M, n, rel, lane, fs, cnt, nb);
            proc_rec(r.w, bbase + 3 < M, n, rel, lane, fs, cnt, nb);
        }
        part[wv][lane] = fs;
        if (lane == 0) { pc[wv] = cnt; pn[wv] = nb; }
        __syncthreads();
        if (wv == 0) {
            fs = part[0][lane] + part[1][lane] + part[2][lane] + part[3][lane];
            cnt = pc[0] + pc[1] + pc[2] + pc[3];
            nb = pn[0] + pn[1] + pn[2] + pn[3];
            float res;
            if (cnt == 0) {
                res = ctxj;                      // relevant, no edges -> rel_ctx
            } else {
                float avg = fs / (float)cnt;
                bool hasnbr = (nb > 0);          // wave-uniform
                const float* W1 = hasnbr ? Wc1 : Wi1;
                const float* b1 = hasnbr ? bc1 : bi1;
                const float* W2 = hasnbr ? Wc2 : Wi2;
                const float* b2 = hasnbr ? bc2 : bi2;
                float h1 = b1[lane];
#pragma unroll 4
                for (int k = 0; k < DD; ++k) {
                    float a_k = __shfl(avg, k);
                    float x2 = hasnbr ? a_k : __shfl(ctxj, k);
                    h1 += a_k * W1[k * DD + lane] + x2 * W1[(DD + k) * DD + lane];
                }
                h1 = fmaxf(h1, 0.f);
                float o = b2[lane];
#pragma unroll 4
                for (int k = 0; k < DD; ++k)
                    o += __shfl(h1, k) * W2[k * DD + lane];
                res = (1.f - alpha) * avg + alpha * o;
            }
            float* p = out + (size_t)n * DD + lane;
            for (int b = 0; b < B; ++b) p[(size_t)b * plane] = res;
        }
        __syncthreads();
    }
}

extern "C" void kernel_launch(void* const* d_in, const int* in_sizes, int n_in,
                              void* d_out, int out_size, void* d_ws, size_t ws_size,
                              hipStream_t stream) {
    const int*   edge_index = (const int*)d_in[0];    // [2, E]
    const int*   edge_type  = (const int*)d_in[1];    // [E]
    const int*   h_index    = (const int*)d_in[2];    // [B]
    const float* rel_emb    = (const float*)d_in[3];  // [R, 64]
    const float* Wi1 = (const float*)d_in[5];
    const float* bi1 = (const float*)d_in[6];
    const float* Wi2 = (const float*)d_in[7];
    const float* bi2 = (const float*)d_in[8];
    const float* Wc1 = (const float*)d_in[9];
    const float* bc1 = (const float*)d_in[10];
    const float* Wc2 = (const float*)d_in[11];
    const float* bc2 = (const float*)d_in[12];
    const float* strength = (const float*)d_in[13];
    float* out = (float*)d_out;

    const int E = in_sizes[1];
    const int B = in_sizes[2];
    const int R = in_sizes[3] / DD;
    const int N = out_size / (B * DD);
    const int NB = (N + 31) / 32;
    const int* src = edge_index;
    const int* dst = edge_index + E;

    char* w = (char*)d_ws;
    size_t off = 0;
    auto carve = [&](size_t bytes) -> char* {
        char* p = w + off;
        off += (bytes + 255) & ~(size_t)255;
        return p;
    };
    float*    ctx      = (float*)carve(DD * sizeof(float));
    int*      counters = (int*)carve(2 * sizeof(int));
    unsigned* bitmap   = (unsigned*)carve((size_t)NB * sizeof(unsigned));
    int*      rel_list = (int*)carve((size_t)N * sizeof(int));
    unsigned* rlist    = (unsigned*)carve(((size_t)2 * E + 512) * sizeof(unsigned));
    (void)ws_size; (void)n_in;

    const int BLK = 256;
    size_t total4 = (size_t)out_size / 4;

    hipLaunchKernelGGL(k_ctx, dim3(1), dim3(512), 0, stream,
                       rel_emb, R, h_index, B, ctx, bitmap, NB, counters);
    hipLaunchKernelGGL(k_markfill, dim3(4096), dim3(BLK), 0, stream,
                       src, dst, h_index, B, bitmap, E, out, total4);
    hipLaunchKernelGGL(k_scan, dim3(1024), dim3(BLK), (size_t)NB * sizeof(unsigned), stream,
                       src, dst, edge_type, bitmap, NB, rel_list, rlist, counters, E);
    hipLaunchKernelGGL(k_gather, dim3(512), dim3(BLK), 0, stream,
                       rel_list, counters, rlist, rel_emb, ctx,
                       Wi1, bi1, Wi2, bi2, Wc1, bc1, Wc2, bc2, strength, out, N, B);
}

// Round 13
// 91.948 us; speedup vs baseline: 1.0414x; 1.0414x over previous
//
#include <hip/hip_runtime.h>

#define DD 64

typedef float f4v __attribute__((ext_vector_type(4)));

// record: node (17b) | etype (9b) | w (1b)
#define PACK(n, t, w) ((((unsigned)(n)) << 10) | (((unsigned)(t)) << 1) | (unsigned)(w))

// Zero-fill [lo4, hi4) float4 slots, plain stores, 4 independent per iter.
__device__ __forceinline__ void fill_zero(float* __restrict__ out, size_t lo4,
                                          size_t hi4, int tid, int nth) {
    f4v z = (f4v)(0.f);
    f4v* p = (f4v*)out;
    size_t stride = (size_t)nth;
    size_t i = lo4 + (size_t)tid;
    for (; i + 3 * stride < hi4; i += 4 * stride) {
        p[i] = z;
        p[i + stride] = z;
        p[i + 2 * stride] = z;
        p[i + 3 * stride] = z;
    }
    for (; i < hi4; i += stride) p[i] = z;
}

// ---------------------------------------------------------------------------
// Node 1: zero bitmap+counters, rel_ctx mean, query-bit marking (one block).
__global__ __launch_bounds__(512) void k_ctx(const float* __restrict__ rel, int R,
                                             const int* __restrict__ h_index, int B,
                                             float* __restrict__ ctx,
                                             unsigned* __restrict__ bitmap, int NB,
                                             int* __restrict__ counters) {
    __shared__ float part[8][DD];
    int t = threadIdx.x;
    for (int i = t; i < NB; i += 512) bitmap[i] = 0u;
    if (t < 2) counters[t] = 0;
    int lane = t & 63;
    int w = t >> 6;
    float s0 = 0.f, s1 = 0.f;
    int r = w;
    for (; r + 16 <= R; r += 16) {
        s0 += rel[(size_t)r * DD + lane];
        s1 += rel[(size_t)(r + 8) * DD + lane];
    }
    for (; r < R; r += 8) s0 += rel[(size_t)r * DD + lane];
    part[w][lane] = s0 + s1;
    __syncthreads();
    if (t < DD) {
        float tot = 0.f;
#pragma unroll
        for (int i = 0; i < 8; ++i) tot += part[i][t];
        ctx[t] = tot / (float)R;
    }
    if (t < B) {
        int n = h_index[t];
        atomicOr(bitmap + ((unsigned)n >> 5), 1u << (n & 31));
    }
}

// ---------------------------------------------------------------------------
// Node 2: mark 1-hop neighbors + fill [0, fA).
__device__ __forceinline__ bool is_q(int v, const int* hq) {
    bool m = false;
#pragma unroll
    for (int b = 0; b < 8; ++b) m |= (v == hq[b]);
    return m;
}

__global__ __launch_bounds__(256) void k_markfill(const int* __restrict__ src,
                                                  const int* __restrict__ dst,
                                                  const int* __restrict__ h_index, int B,
                                                  unsigned* __restrict__ bitmap, int E,
                                                  float* __restrict__ out, size_t fA) {
    int hq[8];
#pragma unroll
    for (int b = 0; b < 8; ++b) hq[b] = (b < B) ? h_index[b] : -1;
    const int nth = gridDim.x * blockDim.x;
    const int tid = blockIdx.x * blockDim.x + threadIdx.x;
    const int E16 = E & ~15;
#define MARK1(sv, dv)                                                        \
    do {                                                                     \
        if (is_q(sv, hq)) atomicOr(bitmap + ((unsigned)(dv) >> 5), 1u << ((dv) & 31)); \
        if (is_q(dv, hq)) atomicOr(bitmap + ((unsigned)(sv) >> 5), 1u << ((sv) & 31)); \
    } while (0)
    for (int base = tid * 16; base < E16; base += nth * 16) {
        int4 s[4], d[4];
#pragma unroll
        for (int u = 0; u < 4; ++u) s[u] = *(const int4*)(src + base + u * 4);
#pragma unroll
        for (int u = 0; u < 4; ++u) d[u] = *(const int4*)(dst + base + u * 4);
#pragma unroll
        for (int u = 0; u < 4; ++u) {
            MARK1(s[u].x, d[u].x); MARK1(s[u].y, d[u].y);
            MARK1(s[u].z, d[u].z); MARK1(s[u].w, d[u].w);
        }
    }
    for (int e = E16 + tid; e < E; e += nth) MARK1(src[e], dst[e]);
#undef MARK1
    fill_zero(out, 0, fA, tid, nth);
}

// ---------------------------------------------------------------------------
// Node 3: compact + edge scan #2 -> packed records + fill [fA, fB).
__global__ __launch_bounds__(256) void k_scanfill(const int* __restrict__ src,
                                                  const int* __restrict__ dst,
                                                  const int* __restrict__ etype,
                                                  const unsigned* __restrict__ bitmap, int NB,
                                                  int* __restrict__ rel_list,
                                                  unsigned* __restrict__ rlist,
                                                  int* __restrict__ counters, int E,
                                                  float* __restrict__ out,
                                                  size_t fA, size_t fB) {
    extern __shared__ unsigned bm[];
    const int lane = threadIdx.x & 63;
    const int tid = blockIdx.x * blockDim.x + threadIdx.x;
    const int nth = gridDim.x * blockDim.x;
    // ---- (a) compact ----
    {
        int i = tid;
        unsigned word = (i < NB) ? bitmap[i] : 0u;
        int c = __popc(word);
        int incl = c;
#pragma unroll
        for (int sh = 1; sh < 64; sh <<= 1) {
            int t = __shfl_up(incl, sh);
            if (lane >= sh) incl += t;
        }
        int total = __shfl(incl, 63);
        if (total > 0) {
            int b0 = 0;
            if (lane == 0) b0 = atomicAdd(counters + 0, total);
            b0 = __shfl(b0, 0);
            int off = b0 + incl - c;
            while (word) {
                int bit = __ffs(word) - 1;
                word &= word - 1;
                rel_list[off++] = i * 32 + bit;
            }
        }
    }
    // ---- (b) scan ----
    for (int i = threadIdx.x; i < NB; i += blockDim.x) bm[i] = bitmap[i];
    __syncthreads();
#define CHK(id) ((bm[(unsigned)(id) >> 5] >> ((unsigned)(id) & 31)) & 1u)
    const int wid = tid >> 6;
    const int nw = nth >> 6;
    const int E16 = E & ~15;
    const int CH = 64 * 16;
    for (int cb = wid * CH; cb < E16; cb += nw * CH) {
        int base = cb + lane * 16;
        bool act = (base < E16);
        int4 s[4], d[4];
        if (act) {
#pragma unroll
            for (int u = 0; u < 4; ++u) s[u] = *(const int4*)(src + base + u * 4);
#pragma unroll
            for (int u = 0; u < 4; ++u) d[u] = *(const int4*)(dst + base + u * 4);
        }
        unsigned ms = 0u, md = 0u;
        if (act) {
#define TST(sv, dv, idx)                                        \
            do {                                                \
                unsigned bs = CHK(sv), bd = CHK(dv);            \
                unsigned neq = ((sv) != (dv)) ? 1u : 0u;        \
                ms |= bs << (idx);                              \
                md |= (bd & neq) << (idx);                      \
            } while (0)
#pragma unroll
            for (int u = 0; u < 4; ++u) {
                TST(s[u].x, d[u].x, u * 4 + 0);
                TST(s[u].y, d[u].y, u * 4 + 1);
                TST(s[u].z, d[u].z, u * 4 + 2);
                TST(s[u].w, d[u].w, u * 4 + 3);
            }
#undef TST
        }
        int c = __popc(ms) + __popc(md);
        int incl = c;
#pragma unroll
        for (int sh = 1; sh < 64; sh <<= 1) {
            int t = __shfl_up(incl, sh);
            if (lane >= sh) incl += t;
        }
        int total = __shfl(incl, 63);
        if (total == 0) continue;
        int b0 = 0;
        if (lane == 0) b0 = atomicAdd(counters + 1, total);
        b0 = __shfl(b0, 0);
        unsigned off = (unsigned)(b0 + incl - c);
        if (c) {
#define EMIT(sv, dv, idx)                                                     \
            do {                                                              \
                unsigned bit = 1u << (idx);                                   \
                if ((ms | md) & bit) {                                        \
                    int t = etype[base + (idx)];                              \
                    if (ms & bit) rlist[off++] = PACK(sv, t, ((sv) != (dv)) ? 1 : 0); \
                    if (md & bit) rlist[off++] = PACK(dv, t, 1);              \
                }                                                             \
            } while (0)
#pragma unroll
            for (int u = 0; u < 4; ++u) {
                EMIT(s[u].x, d[u].x, u * 4 + 0);
                EMIT(s[u].y, d[u].y, u * 4 + 1);
                EMIT(s[u].z, d[u].z, u * 4 + 2);
                EMIT(s[u].w, d[u].w, u * 4 + 3);
            }
#undef EMIT
        }
    }
    for (int e = E16 + tid; e < E; e += nth) {
        int sv = src[e], dv = dst[e];
        unsigned bs = CHK(sv), bd = CHK(dv);
        unsigned neq = (sv != dv) ? 1u : 0u;
        int k = (int)bs + (int)(bd & neq);
        if (k) {
            int t = etype[e];
            int o = atomicAdd(counters + 1, k);
            if (bs) rlist[o++] = PACK(sv, t, neq);
            if (bd & neq) rlist[o] = PACK(dv, t, 1);
        }
    }
#undef CHK
    fill_zero(out, fA, fB, tid, nth);
}

// ---------------------------------------------------------------------------
// Node 4: fill [fB, total4) skipping relevant rows, + gather+MLP+write B planes.
// Relevant rows in [fB,total4) are written ONLY by their gather block -> no race.
__device__ __forceinline__ void proc_rec(unsigned rv, bool valid, int n,
                                         const float* __restrict__ rel, int lane,
                                         float& fs, int& cnt, int& nb) {
    bool want = valid && ((int)(rv >> 10) == n);
    unsigned long long mk = __ballot(want);
    while (mk) {
        int l = __ffsll(mk) - 1;
        mk &= mk - 1;
        unsigned v = __shfl(rv, l);
        int t = (int)((v >> 1) & 0x1FFu);
        fs += rel[t * DD + lane];
        cnt += 1;
        nb += (int)(v & 1u);
    }
}

__global__ __launch_bounds__(256) void k_gatherfill(
    const int* __restrict__ rel_list, const int* __restrict__ counters,
    const unsigned* __restrict__ rlist, const unsigned* __restrict__ bitmap,
    const float* __restrict__ rel, const float* __restrict__ ctx,
    const float* __restrict__ Wi1, const float* __restrict__ bi1,
    const float* __restrict__ Wi2, const float* __restrict__ bi2,
    const float* __restrict__ Wc1, const float* __restrict__ bc1,
    const float* __restrict__ Wc2, const float* __restrict__ bc2,
    const float* __restrict__ strength, float* __restrict__ out, int N, int B,
    size_t fB, size_t total4) {
    const int tid = blockIdx.x * blockDim.x + threadIdx.x;
    const int nth = gridDim.x * blockDim.x;
    // ---- fill [fB, total4), skipping relevant rows (bitmap-tested) ----
    {
        f4v z = (f4v)(0.f);
        f4v* p = (f4v*)out;
        size_t i = fB + (size_t)tid;              // fB is 16-f4 (row) aligned
        if (i < total4) {
            unsigned row = (unsigned)(i >> 4);    // global row (plane*N + n)
            unsigned n = row;
            while (n >= (unsigned)N) n -= (unsigned)N;   // row < 8N: <=7 subs
            unsigned dn = (unsigned)(nth >> 4);   // nth multiple of 16
            while (dn >= (unsigned)N) dn -= (unsigned)N;
            for (; i < total4; i += (size_t)nth) {
                if (!((bitmap[n >> 5] >> (n & 31)) & 1u)) p[i] = z;
                n += dn;
                if (n >= (unsigned)N) n -= (unsigned)N;
            }
        }
    }
    // ---- gather + MLP + write B planes ----
    __shared__ float part[4][DD];
    __shared__ int pc[4], pn[4];
    int lane = threadIdx.x & 63;
    int wv = threadIdx.x >> 6;
    int C = counters[0];
    int M = counters[1];
    float alpha = fminf(fmaxf(strength[0], 0.f), 0.3f);
    float ctxj = ctx[lane];
    int nchunk = (M + 255) / 256;
    size_t plane = (size_t)N * DD;
    for (int i = blockIdx.x; i < C; i += gridDim.x) {
        int n = rel_list[i];
        float fs = 0.f;
        int cnt = 0, nb = 0;
        for (int ch = wv; ch < nchunk; ch += 4) {
            int bbase = ch * 256 + lane * 4;
            uint4 r = *(const uint4*)(rlist + bbase);   // capacity-padded
            proc_rec(r.x, bbase + 0 < M, n, rel, lane, fs, cnt, nb);
            proc_rec(r.y, bbase + 1 < M, n, rel, lane, fs, cnt, nb);
            proc_rec(r.z, bbase + 2 < M, n, rel, lane, fs, cnt, nb);
            proc_rec(r.w, bbase + 3 < M, n, rel, lane, fs, cnt, nb);
        }
        part[wv][lane] = fs;
        if (lane == 0) { pc[wv] = cnt; pn[wv] = nb; }
        __syncthreads();
        if (wv == 0) {
            fs = part[0][lane] + part[1][lane] + part[2][lane] + part[3][lane];
            cnt = pc[0] + pc[1] + pc[2] + pc[3];
            nb = pn[0] + pn[1] + pn[2] + pn[3];
            float res;
            if (cnt == 0) {
                res = ctxj;                      // relevant, no edges -> rel_ctx
            } else {
                float avg = fs / (float)cnt;
                bool hasnbr = (nb > 0);          // wave-uniform
                const float* W1 = hasnbr ? Wc1 : Wi1;
                const float* b1 = hasnbr ? bc1 : bi1;
                const float* W2 = hasnbr ? Wc2 : Wi2;
                const float* b2 = hasnbr ? bc2 : bi2;
                float h1 = b1[lane];
#pragma unroll 4
                for (int k = 0; k < DD; ++k) {
                    float a_k = __shfl(avg, k);
                    float x2 = hasnbr ? a_k : __shfl(ctxj, k);
                    h1 += a_k * W1[k * DD + lane] + x2 * W1[(DD + k) * DD + lane];
                }
                h1 = fmaxf(h1, 0.f);
                float o = b2[lane];
#pragma unroll 4
                for (int k = 0; k < DD; ++k)
                    o += __shfl(h1, k) * W2[k * DD + lane];
                res = (1.f - alpha) * avg + alpha * o;
            }
            float* p = out + (size_t)n * DD + lane;
            for (int b = 0; b < B; ++b) p[(size_t)b * plane] = res;
        }
        __syncthreads();
    }
}

extern "C" void kernel_launch(void* const* d_in, const int* in_sizes, int n_in,
                              void* d_out, int out_size, void* d_ws, size_t ws_size,
                              hipStream_t stream) {
    const int*   edge_index = (const int*)d_in[0];    // [2, E]
    const int*   edge_type  = (const int*)d_in[1];    // [E]
    const int*   h_index    = (const int*)d_in[2];    // [B]
    const float* rel_emb    = (const float*)d_in[3];  // [R, 64]
    const float* Wi1 = (const float*)d_in[5];
    const float* bi1 = (const float*)d_in[6];
    const float* Wi2 = (const float*)d_in[7];
    const float* bi2 = (const float*)d_in[8];
    const float* Wc1 = (const float*)d_in[9];
    const float* bc1 = (const float*)d_in[10];
    const float* Wc2 = (const float*)d_in[11];
    const float* bc2 = (const float*)d_in[12];
    const float* strength = (const float*)d_in[13];
    float* out = (float*)d_out;

    const int E = in_sizes[1];
    const int B = in_sizes[2];
    const int R = in_sizes[3] / DD;
    const int N = out_size / (B * DD);
    const int NB = (N + 31) / 32;
    const int* src = edge_index;
    const int* dst = edge_index + E;

    char* w = (char*)d_ws;
    size_t off = 0;
    auto carve = [&](size_t bytes) -> char* {
        char* p = w + off;
        off += (bytes + 255) & ~(size_t)255;
        return p;
    };
    float*    ctx      = (float*)carve(DD * sizeof(float));
    int*      counters = (int*)carve(2 * sizeof(int));
    unsigned* bitmap   = (unsigned*)carve((size_t)NB * sizeof(unsigned));
    int*      rel_list = (int*)carve((size_t)N * sizeof(int));
    unsigned* rlist    = (unsigned*)carve(((size_t)2 * E + 512) * sizeof(unsigned));
    (void)ws_size; (void)n_in;

    const int BLK = 256;
    size_t total4 = (size_t)out_size / 4;              // float4 count
    size_t fA = (total4 * 2 / 5) & ~(size_t)15;        // 40%, row-aligned
    size_t fB = (total4 * 3 / 4) & ~(size_t)15;        // +35%, row-aligned

    hipLaunchKernelGGL(k_ctx, dim3(1), dim3(512), 0, stream,
                       rel_emb, R, h_index, B, ctx, bitmap, NB, counters);
    hipLaunchKernelGGL(k_markfill, dim3(4096), dim3(BLK), 0, stream,
                       src, dst, h_index, B, bitmap, E, out, fA);
    hipLaunchKernelGGL(k_scanfill, dim3(4096), dim3(BLK), (size_t)NB * sizeof(unsigned), stream,
                       src, dst, edge_type, bitmap, NB, rel_list, rlist, counters, E,
                       out, fA, fB);
    hipLaunchKernelGGL(k_gatherfill, dim3(2048), dim3(BLK), 0, stream,
                       rel_list, counters, rlist, bitmap, rel_emb, ctx,
                       Wi1, bi1, Wi2, bi2, Wc1, bc1, Wc2, bc2, strength, out, N, B,
                       fB, total4);
}